// Round 2
// baseline (1343.039 us; speedup 1.0000x reference)
//
#include <hip/hip_runtime.h>
#include <cstdint>

#define NTOK 8192
#define DIM  1024
#define NEXP 8
#define NF   3264
#define NPAIR (NTOK*2)
#define TM 128
#define BK 64
#define ASTRIDE (BK+8)
#define MAXTILES 136

typedef __attribute__((ext_vector_type(8))) short short8;
typedef __attribute__((ext_vector_type(4))) float f32x4;

__device__ __forceinline__ unsigned short f2bf(float f){
    unsigned u = __float_as_uint(f);
    return (unsigned short)((u + 0x7FFFu + ((u >> 16) & 1u)) >> 16);
}
__device__ __forceinline__ unsigned pk2(float a, float b){
    return (unsigned)f2bf(a) | ((unsigned)f2bf(b) << 16);
}
__device__ __forceinline__ uint4 cvt8(const float* p){
    const float4* q = (const float4*)p;
    float4 a = q[0], b = q[1];
    uint4 r;
    r.x = pk2(a.x, a.y); r.y = pk2(a.z, a.w);
    r.z = pk2(b.x, b.y); r.w = pk2(b.z, b.w);
    return r;
}

__global__ __launch_bounds__(256) void k_cvt(const float4* __restrict__ src,
                                             uint2* __restrict__ dst, int n4){
    int i = blockIdx.x * 256 + threadIdx.x;
    if (i >= n4) return;
    float4 a = src[i];
    uint2 r; r.x = pk2(a.x, a.y); r.y = pk2(a.z, a.w);
    dst[i] = r;
}

__global__ __launch_bounds__(256) void k_zero_f4(float4* __restrict__ p, int n4){
    int i = blockIdx.x * 256 + threadIdx.x;
    if (i < n4) p[i] = make_float4(0.f, 0.f, 0.f, 0.f);
}

__global__ void k_zero_ctrl(int* ctrl){
    if (threadIdx.x < 64) ctrl[threadIdx.x] = 0;
}

// ctrl layout: [0..7]=counts, [8..16]=offsets, [17..25]=tileOff, [26..33]=cursor
__global__ __launch_bounds__(256) void k_router(const float* __restrict__ x,
        const float* __restrict__ gw, const float* __restrict__ gb,
        int* __restrict__ top_idx, float* __restrict__ top_w, int* __restrict__ ctrl){
    int wave = threadIdx.x >> 6;
    int lane = threadIdx.x & 63;
    int n = blockIdx.x * 4 + wave;
    const float* xr = x + (size_t)n * DIM;
    float acc[NEXP];
    #pragma unroll
    for (int e = 0; e < NEXP; e++) acc[e] = 0.f;
    for (int j = lane; j < DIM; j += 64){
        float xv = xr[j];
        #pragma unroll
        for (int e = 0; e < NEXP; e++) acc[e] += xv * gw[e * DIM + j];
    }
    #pragma unroll
    for (int e = 0; e < NEXP; e++){
        float v = acc[e];
        #pragma unroll
        for (int off = 32; off > 0; off >>= 1) v += __shfl_xor(v, off);
        acc[e] = v + gb[e];
    }
    if (lane == 0){
        int i0 = 0; float m0 = acc[0];
        #pragma unroll
        for (int e = 1; e < NEXP; e++) if (acc[e] > m0){ m0 = acc[e]; i0 = e; }
        int i1 = -1; float m1 = -3.4e38f;
        #pragma unroll
        for (int e = 0; e < NEXP; e++) if (e != i0 && acc[e] > m1){ m1 = acc[e]; i1 = e; }
        float b  = __expf(m1 - m0);
        float w0 = 1.f / (1.f + b);
        float w1 = b / (1.f + b);
        top_idx[n * 2] = i0; top_idx[n * 2 + 1] = i1;
        top_w[n * 2] = w0;  top_w[n * 2 + 1] = w1;
        atomicAdd(&ctrl[i0], 1);
        atomicAdd(&ctrl[i1], 1);
    }
}

__global__ void k_prefix(int* ctrl){
    int* counts = ctrl; int* offsets = ctrl + 8; int* tileOff = ctrl + 17; int* cursor = ctrl + 26;
    offsets[0] = 0; tileOff[0] = 0;
    for (int e = 0; e < NEXP; e++){
        offsets[e + 1] = offsets[e] + counts[e];
        tileOff[e + 1] = tileOff[e] + (counts[e] + TM - 1) / TM;
        cursor[e] = 0;
    }
}

__global__ __launch_bounds__(256) void k_scatter(const int* __restrict__ top_idx,
        const float* __restrict__ top_w, int* __restrict__ ctrl,
        int* __restrict__ pair_token, float* __restrict__ pair_w){
    const int* offsets = ctrl + 8;
    int* cursor = ctrl + 26;
    int n = blockIdx.x * 256 + threadIdx.x;
    if (n >= NTOK) return;
    #pragma unroll
    for (int k = 0; k < 2; k++){
        int e = top_idx[n * 2 + k];
        int p = atomicAdd(&cursor[e], 1);
        int slot = offsets[e] + p;
        pair_token[slot] = n;
        pair_w[slot] = top_w[n * 2 + k];
    }
}

// GEMM1: h[tile-local slot, f] = silu((x@gpW^T)*(x@upW^T)) bf16.
// hbuf is chunk-local: row = blockIdx.x*TM + m.
template<bool WB, bool XB>
__global__ __launch_bounds__(256) void k_gemm1(
        const float* __restrict__ xf, const unsigned short* __restrict__ xb,
        const unsigned short* __restrict__ wg, const unsigned short* __restrict__ wu,
        const float* __restrict__ wgf, const float* __restrict__ wuf,
        const float* __restrict__ gpb, const float* __restrict__ upb,
        const int* __restrict__ pair_token, const int* __restrict__ ctrl,
        unsigned short* __restrict__ hbuf, int t0){
    const int* offsets = ctrl + 8;
    const int* tileOff = ctrl + 17;
    int g = t0 + blockIdx.x;
    if (g >= tileOff[NEXP]) return;
    int e = 0;
    while (e < NEXP - 1 && g >= tileOff[e + 1]) e++;
    int row0 = (g - tileOff[e]) * TM;
    int nrows = offsets[e + 1] - offsets[e];
    int base_slot = offsets[e] + row0;
    int f0 = blockIdx.y * 64;
    int lt = blockIdx.x;   // chunk-local tile index for hbuf addressing

    __shared__ unsigned short As[TM][ASTRIDE];
    __shared__ unsigned short Bs[TM][ASTRIDE];

    int tid = threadIdx.x;
    int sr = tid >> 3, sc = tid & 7;

    const unsigned short* a_src[4];
    const float* a_srcf[4];
    bool a_val[4];
    #pragma unroll
    for (int it = 0; it < 4; it++){
        int r = it * 32 + sr;
        bool v = (row0 + r) < nrows;
        int tok = v ? (pair_token[base_slot + r] & (NTOK - 1)) : 0;
        a_val[it] = v;
        if (XB) a_src[it]  = xb + (size_t)tok * DIM + sc * 8;
        else    a_srcf[it] = xf + (size_t)tok * DIM + sc * 8;
    }
    const unsigned short* b_src[4];
    const float* b_srcf[4];
    #pragma unroll
    for (int it = 0; it < 4; it++){
        int br = it * 32 + sr;
        int f = f0 + ((br >> 5) << 4) + (br & 15);
        bool up = (br >> 4) & 1;
        size_t woff = ((size_t)e * NF + f) * DIM + sc * 8;
        if (WB) b_src[it]  = (up ? wu : wg) + woff;
        else    b_srcf[it] = (up ? wuf : wgf) + woff;
    }

    int lane = tid & 63, wave = tid >> 6;
    int wr64 = (wave >> 1) * 64, wc = wave & 1, wc64 = wc * 64;
    int lr = lane & 15, q = lane >> 4;

    f32x4 acc[4][4];
    #pragma unroll
    for (int i = 0; i < 4; i++)
        #pragma unroll
        for (int j = 0; j < 4; j++) acc[i][j] = (f32x4){0.f, 0.f, 0.f, 0.f};

    for (int kb = 0; kb < DIM / BK; kb++){
        int k0 = kb * BK;
        #pragma unroll
        for (int it = 0; it < 4; it++){
            uint4 v = make_uint4(0u, 0u, 0u, 0u);
            if (a_val[it]){
                if (XB) v = *(const uint4*)(a_src[it] + k0);
                else    v = cvt8(a_srcf[it] + k0);
            }
            *(uint4*)&As[it * 32 + sr][sc * 8] = v;
        }
        #pragma unroll
        for (int it = 0; it < 4; it++){
            uint4 v;
            if (WB) v = *(const uint4*)(b_src[it] + k0);
            else    v = cvt8(b_srcf[it] + k0);
            *(uint4*)&Bs[it * 32 + sr][sc * 8] = v;
        }
        __syncthreads();
        #pragma unroll
        for (int kk = 0; kk < 2; kk++){
            short8 av[4], bv[4];
            #pragma unroll
            for (int mf = 0; mf < 4; mf++) av[mf] = *(const short8*)&As[wr64 + mf * 16 + lr][kk * 32 + q * 8];
            #pragma unroll
            for (int nf = 0; nf < 4; nf++) bv[nf] = *(const short8*)&Bs[wc64 + nf * 16 + lr][kk * 32 + q * 8];
            #pragma unroll
            for (int mf = 0; mf < 4; mf++)
                #pragma unroll
                for (int nf = 0; nf < 4; nf++)
                    acc[mf][nf] = __builtin_amdgcn_mfma_f32_16x16x32_bf16(av[mf], bv[nf], acc[mf][nf], 0, 0, 0);
        }
        __syncthreads();
    }

    #pragma unroll
    for (int mf = 0; mf < 4; mf++){
        #pragma unroll
        for (int fp = 0; fp < 2; fp++){
            int fcol = f0 + (wc * 2 + fp) * 16 + lr;
            float gb_ = gpb[e * NF + fcol];
            float ub_ = upb[e * NF + fcol];
            #pragma unroll
            for (int r = 0; r < 4; r++){
                int m = wr64 + mf * 16 + q * 4 + r;
                if (row0 + m < nrows){
                    float gv = acc[mf][2 * fp][r] + gb_;
                    float uv = acc[mf][2 * fp + 1][r] + ub_;
                    float z = gv * uv;
                    float h = z / (1.f + __expf(-z));
                    hbuf[((size_t)(lt * TM + m)) * NF + fcol] = f2bf(h);
                }
            }
        }
    }
}

// GEMM2: out[token, :] += w * (h @ downW^T + down_b). hbuf chunk-local rows.
template<bool WB>
__global__ __launch_bounds__(256) void k_gemm2(
        const unsigned short* __restrict__ hbuf,
        const unsigned short* __restrict__ wd, const float* __restrict__ wdf,
        const float* __restrict__ db,
        const int* __restrict__ pair_token, const float* __restrict__ pair_w,
        const int* __restrict__ ctrl, float* __restrict__ out, int t0){
    const int* offsets = ctrl + 8;
    const int* tileOff = ctrl + 17;
    int g = t0 + blockIdx.x;
    if (g >= tileOff[NEXP]) return;
    int e = 0;
    while (e < NEXP - 1 && g >= tileOff[e + 1]) e++;
    int row0 = (g - tileOff[e]) * TM;
    int nrows = offsets[e + 1] - offsets[e];
    int base_slot = offsets[e] + row0;
    int n0 = blockIdx.y * TM;
    int lt = blockIdx.x;

    __shared__ unsigned short As[TM][ASTRIDE];
    __shared__ unsigned short Bs[TM][ASTRIDE];

    int tid = threadIdx.x;
    int sr = tid >> 3, sc = tid & 7;

    const unsigned short* a_src[4]; bool a_val[4];
    #pragma unroll
    for (int it = 0; it < 4; it++){
        int r = it * 32 + sr;
        a_val[it] = (row0 + r) < nrows;
        a_src[it] = hbuf + ((size_t)(lt * TM + r)) * NF + sc * 8;
    }
    const unsigned short* b_src[4];
    const float* b_srcf[4];
    #pragma unroll
    for (int it = 0; it < 4; it++){
        int d = n0 + it * 32 + sr;
        size_t woff = ((size_t)e * DIM + d) * NF + sc * 8;
        if (WB) b_src[it]  = wd + woff;
        else    b_srcf[it] = wdf + woff;
    }

    int lane = tid & 63, wave = tid >> 6;
    int wr64 = (wave >> 1) * 64, wc = wave & 1, wc64 = wc * 64;
    int lr = lane & 15, q = lane >> 4;

    f32x4 acc[4][4];
    #pragma unroll
    for (int i = 0; i < 4; i++)
        #pragma unroll
        for (int j = 0; j < 4; j++) acc[i][j] = (f32x4){0.f, 0.f, 0.f, 0.f};

    for (int kb = 0; kb < NF / BK; kb++){
        int k0 = kb * BK;
        #pragma unroll
        for (int it = 0; it < 4; it++){
            uint4 v = make_uint4(0u, 0u, 0u, 0u);
            if (a_val[it]) v = *(const uint4*)(a_src[it] + k0);
            *(uint4*)&As[it * 32 + sr][sc * 8] = v;
        }
        #pragma unroll
        for (int it = 0; it < 4; it++){
            uint4 v;
            if (WB) v = *(const uint4*)(b_src[it] + k0);
            else    v = cvt8(b_srcf[it] + k0);
            *(uint4*)&Bs[it * 32 + sr][sc * 8] = v;
        }
        __syncthreads();
        #pragma unroll
        for (int kk = 0; kk < 2; kk++){
            short8 av[4], bv[4];
            #pragma unroll
            for (int mf = 0; mf < 4; mf++) av[mf] = *(const short8*)&As[wr64 + mf * 16 + lr][kk * 32 + q * 8];
            #pragma unroll
            for (int nf = 0; nf < 4; nf++) bv[nf] = *(const short8*)&Bs[wc64 + nf * 16 + lr][kk * 32 + q * 8];
            #pragma unroll
            for (int mf = 0; mf < 4; mf++)
                #pragma unroll
                for (int nf = 0; nf < 4; nf++)
                    acc[mf][nf] = __builtin_amdgcn_mfma_f32_16x16x32_bf16(av[mf], bv[nf], acc[mf][nf], 0, 0, 0);
        }
        __syncthreads();
    }

    #pragma unroll
    for (int mf = 0; mf < 4; mf++){
        #pragma unroll
        for (int r = 0; r < 4; r++){
            int m = wr64 + mf * 16 + q * 4 + r;
            if (row0 + m < nrows){
                int slot = base_slot + m;
                int tok = pair_token[slot] & (NTOK - 1);
                float w = pair_w[slot];
                #pragma unroll
                for (int nf = 0; nf < 4; nf++){
                    int n = n0 + wc64 + nf * 16 + lr;
                    float v = w * (acc[mf][nf][r] + db[e * DIM + n]);
                    atomicAdd(&out[(size_t)tok * DIM + n], v);
                }
            }
        }
    }
}

extern "C" void kernel_launch(void* const* d_in, const int* in_sizes, int n_in,
                              void* d_out, int out_size, void* d_ws, size_t ws_size,
                              hipStream_t stream){
    (void)in_sizes; (void)n_in; (void)out_size;
    const float* x      = (const float*)d_in[0];
    const float* gate_w = (const float*)d_in[1];
    const float* gate_b = (const float*)d_in[2];
    const float* up_w   = (const float*)d_in[3];
    const float* up_b   = (const float*)d_in[4];
    const float* gp_w   = (const float*)d_in[5];
    const float* gp_b   = (const float*)d_in[6];
    const float* down_w = (const float*)d_in[7];
    const float* down_b = (const float*)d_in[8];
    float* out = (float*)d_out;
    char* ws = (char*)d_ws;

    const size_t SZ_XB   = (size_t)NTOK * DIM * 2;             // 16.8 MB
    const size_t SZ_W    = (size_t)NEXP * NF * DIM * 2;        // 53.5 MB each
    const size_t TILE_SZ = (size_t)TM * NF * 2;                // 835,584 B

    // fixed small region (always present)
    size_t off = 0;
    int*   ctrl       = (int*)(ws + off);   off += 256;
    int*   pair_token = (int*)(ws + off);   off += (size_t)NPAIR * 4;
    float* pair_w     = (float*)(ws + off); off += (size_t)NPAIR * 4;
    int*   top_idx    = (int*)(ws + off);   off += (size_t)NTOK * 2 * 4;
    float* top_w      = (float*)(ws + off); off += (size_t)NTOK * 2 * 4;

    size_t rem = (ws_size > off) ? (ws_size - off) : 0;
    bool XB = false, WB = false;
    unsigned short* xb = nullptr;
    unsigned short *wg = nullptr, *wu = nullptr, *wd = nullptr;

    if (rem >= SZ_XB + TILE_SZ){                // bf16 x worth it if >=1-tile hbuf still fits
        XB = true;
        xb = (unsigned short*)(ws + off); off += SZ_XB; rem -= SZ_XB;
    }
    if (rem >= 3 * SZ_W + (size_t)MAXTILES * TILE_SZ){   // bf16 weights only with full hbuf
        WB = true;
        wg = (unsigned short*)(ws + off); off += SZ_W;
        wu = (unsigned short*)(ws + off); off += SZ_W;
        wd = (unsigned short*)(ws + off); off += SZ_W;
        rem -= 3 * SZ_W;
    }
    int TC = (int)((rem / TILE_SZ) < (size_t)MAXTILES ? (rem / TILE_SZ) : (size_t)MAXTILES);
    if (TC < 1) TC = 1;                          // ws too small to be correct; avoid div0
    unsigned short* hbuf = (unsigned short*)(ws + off);
    int NCH = (MAXTILES + TC - 1) / TC;

    int out_n4 = NTOK * DIM / 4;
    k_zero_f4<<<(out_n4 + 255) / 256, 256, 0, stream>>>((float4*)out, out_n4);
    k_zero_ctrl<<<1, 64, 0, stream>>>(ctrl);
    if (XB)
        k_cvt<<<(out_n4 + 255) / 256, 256, 0, stream>>>((const float4*)x, (uint2*)xb, out_n4);
    if (WB){
        int n4 = NEXP * NF * DIM / 4;
        int gc = (n4 + 255) / 256;
        k_cvt<<<gc, 256, 0, stream>>>((const float4*)gp_w,   (uint2*)wg, n4);
        k_cvt<<<gc, 256, 0, stream>>>((const float4*)up_w,   (uint2*)wu, n4);
        k_cvt<<<gc, 256, 0, stream>>>((const float4*)down_w, (uint2*)wd, n4);
    }
    k_router<<<NTOK / 4, 256, 0, stream>>>(x, gate_w, gate_b, top_idx, top_w, ctrl);
    k_prefix<<<1, 1, 0, stream>>>(ctrl);
    k_scatter<<<NTOK / 256, 256, 0, stream>>>(top_idx, top_w, ctrl, pair_token, pair_w);

    dim3 g1((unsigned)TC, NF / 64);
    dim3 g2((unsigned)TC, DIM / TM);
    for (int c = 0; c < NCH; c++){
        int t0 = c * TC;
        if (WB){
            if (XB) k_gemm1<true, true ><<<g1, 256, 0, stream>>>(x, xb, wg, wu, nullptr, nullptr, gp_b, up_b, pair_token, ctrl, hbuf, t0);
            else    k_gemm1<true, false><<<g1, 256, 0, stream>>>(x, xb, wg, wu, nullptr, nullptr, gp_b, up_b, pair_token, ctrl, hbuf, t0);
            k_gemm2<true ><<<g2, 256, 0, stream>>>(hbuf, wd, nullptr, down_b, pair_token, pair_w, ctrl, out, t0);
        } else {
            if (XB) k_gemm1<false, true ><<<g1, 256, 0, stream>>>(x, xb, nullptr, nullptr, gp_w, up_w, gp_b, up_b, pair_token, ctrl, hbuf, t0);
            else    k_gemm1<false, false><<<g1, 256, 0, stream>>>(x, xb, nullptr, nullptr, gp_w, up_w, gp_b, up_b, pair_token, ctrl, hbuf, t0);
            k_gemm2<false><<<g2, 256, 0, stream>>>(hbuf, nullptr, down_w, down_b, pair_token, pair_w, ctrl, out, t0);
        }
    }
}

// Round 3
// 1156.422 us; speedup vs baseline: 1.1614x; 1.1614x over previous
//
#include <hip/hip_runtime.h>
#include <cstdint>

#define NTOK 8192
#define DIM  1024
#define NEXP 8
#define NF   3264
#define NPAIR (NTOK*2)
#define TM 128
#define BK 64
#define ASTRIDE (BK+8)
#define MAXTILES 136

typedef __attribute__((ext_vector_type(8))) short short8;
typedef __attribute__((ext_vector_type(4))) float f32x4;

__device__ __forceinline__ unsigned short f2bf(float f){
    unsigned u = __float_as_uint(f);
    return (unsigned short)((u + 0x7FFFu + ((u >> 16) & 1u)) >> 16);
}
__device__ __forceinline__ unsigned pk2(float a, float b){
    return (unsigned)f2bf(a) | ((unsigned)f2bf(b) << 16);
}
__device__ __forceinline__ uint4 cvt8(const float* p){
    const float4* q = (const float4*)p;
    float4 a = q[0], b = q[1];
    uint4 r;
    r.x = pk2(a.x, a.y); r.y = pk2(a.z, a.w);
    r.z = pk2(b.x, b.y); r.w = pk2(b.z, b.w);
    return r;
}

// async global->LDS, 16B per lane; LDS dest = wave-uniform base + lane*16
__device__ __forceinline__ void gload16(const void* g, void* l){
    __builtin_amdgcn_global_load_lds(
        (const __attribute__((address_space(1))) unsigned int*)g,
        (__attribute__((address_space(3))) unsigned int*)l,
        16, 0, 0);
}

__global__ __launch_bounds__(256) void k_cvt(const float4* __restrict__ src,
                                             uint2* __restrict__ dst, int n4){
    int i = blockIdx.x * 256 + threadIdx.x;
    if (i >= n4) return;
    float4 a = src[i];
    uint2 r; r.x = pk2(a.x, a.y); r.y = pk2(a.z, a.w);
    dst[i] = r;
}

__global__ __launch_bounds__(256) void k_zero_f4(float4* __restrict__ p, int n4){
    int i = blockIdx.x * 256 + threadIdx.x;
    if (i < n4) p[i] = make_float4(0.f, 0.f, 0.f, 0.f);
}

__global__ void k_zero_ctrl(int* ctrl){
    if (threadIdx.x < 64) ctrl[threadIdx.x] = 0;
}

// ctrl layout: [0..7]=counts, [8..16]=offsets, [17..25]=tileOff, [26..33]=cursor
template<bool XB>
__global__ __launch_bounds__(256) void k_router(const float* __restrict__ x,
        const float* __restrict__ gw, const float* __restrict__ gb,
        int* __restrict__ top_idx, float* __restrict__ top_w, int* __restrict__ ctrl,
        unsigned short* __restrict__ xb){
    int wave = threadIdx.x >> 6;
    int lane = threadIdx.x & 63;
    int n = blockIdx.x * 4 + wave;
    const float* xr = x + (size_t)n * DIM;
    float acc[NEXP];
    #pragma unroll
    for (int e = 0; e < NEXP; e++) acc[e] = 0.f;
    for (int j = lane; j < DIM; j += 64){
        float xv = xr[j];
        if (XB) xb[(size_t)n * DIM + j] = f2bf(xv);
        #pragma unroll
        for (int e = 0; e < NEXP; e++) acc[e] += xv * gw[e * DIM + j];
    }
    #pragma unroll
    for (int e = 0; e < NEXP; e++){
        float v = acc[e];
        #pragma unroll
        for (int off = 32; off > 0; off >>= 1) v += __shfl_xor(v, off);
        acc[e] = v + gb[e];
    }
    if (lane == 0){
        int i0 = 0; float m0 = acc[0];
        #pragma unroll
        for (int e = 1; e < NEXP; e++) if (acc[e] > m0){ m0 = acc[e]; i0 = e; }
        int i1 = -1; float m1 = -3.4e38f;
        #pragma unroll
        for (int e = 0; e < NEXP; e++) if (e != i0 && acc[e] > m1){ m1 = acc[e]; i1 = e; }
        float b  = __expf(m1 - m0);
        float w0 = 1.f / (1.f + b);
        float w1 = b / (1.f + b);
        top_idx[n * 2] = i0; top_idx[n * 2 + 1] = i1;
        top_w[n * 2] = w0;  top_w[n * 2 + 1] = w1;
        atomicAdd(&ctrl[i0], 1);
        atomicAdd(&ctrl[i1], 1);
    }
}

__global__ void k_prefix(int* ctrl){
    int* counts = ctrl; int* offsets = ctrl + 8; int* tileOff = ctrl + 17; int* cursor = ctrl + 26;
    offsets[0] = 0; tileOff[0] = 0;
    for (int e = 0; e < NEXP; e++){
        offsets[e + 1] = offsets[e] + counts[e];
        tileOff[e + 1] = tileOff[e] + (counts[e] + TM - 1) / TM;
        cursor[e] = 0;
    }
}

__global__ __launch_bounds__(256) void k_scatter(const int* __restrict__ top_idx,
        const float* __restrict__ top_w, int* __restrict__ ctrl,
        int* __restrict__ pair_token, float* __restrict__ pair_w){
    const int* offsets = ctrl + 8;
    int* cursor = ctrl + 26;
    int n = blockIdx.x * 256 + threadIdx.x;
    if (n >= NTOK) return;
    #pragma unroll
    for (int k = 0; k < 2; k++){
        int e = top_idx[n * 2 + k];
        int p = atomicAdd(&cursor[e], 1);
        int slot = offsets[e] + p;
        pair_token[slot] = n;
        pair_w[slot] = top_w[n * 2 + k];
    }
}

// ---------------- fast path: global_load_lds + swizzled LDS ----------------
// LDS layout: unpadded [128][64] bf16; chunk c (16B) of row r stored at slot c^(r&7).
// Swizzle applied via the global source address, so DMA lane order stays base+lane*16.

__global__ __launch_bounds__(256) void k_gemm1_dma(
        const unsigned short* __restrict__ xb,
        const unsigned short* __restrict__ wg, const unsigned short* __restrict__ wu,
        const float* __restrict__ gpb, const float* __restrict__ upb,
        const int* __restrict__ pair_token, const int* __restrict__ ctrl,
        unsigned short* __restrict__ hbuf){
    const int* offsets = ctrl + 8;
    const int* tileOff = ctrl + 17;
    int g = blockIdx.x;
    if (g >= tileOff[NEXP]) return;
    int e = 0;
    while (e < NEXP - 1 && g >= tileOff[e + 1]) e++;
    int row0 = (g - tileOff[e]) * TM;
    int nrows = offsets[e + 1] - offsets[e];
    int base_slot = offsets[e] + row0;
    int f0 = blockIdx.y * 64;
    int lt = blockIdx.x;

    __shared__ __align__(16) unsigned short As[TM][BK];
    __shared__ __align__(16) unsigned short Bs[TM][BK];

    int tid = threadIdx.x;
    int lane = tid & 63;
    int wave = __builtin_amdgcn_readfirstlane(tid >> 6);
    int rsub = lane >> 3;             // row within 8-row chunk group
    int cd = (lane & 7) ^ rsub;       // swizzled source chunk

    const unsigned short* a_g[4];
    const unsigned short* b_g[4];
    char* lA[4]; char* lB[4];
    #pragma unroll
    for (int j = 0; j < 4; j++){
        int chunk = wave * 4 + j;     // 0..15
        int row = chunk * 8 + rsub;   // 0..127
        int rr = (row0 + row < nrows) ? row : 0;   // clamp: garbage only feeds discarded rows
        int tok = pair_token[base_slot + rr] & (NTOK - 1);
        a_g[j] = xb + (size_t)tok * DIM + cd * 8;
        int f = f0 + ((row >> 5) << 4) + (row & 15);
        int up = (row >> 4) & 1;
        b_g[j] = (up ? wu : wg) + ((size_t)e * NF + f) * DIM + cd * 8;
        lA[j] = (char*)As + chunk * 1024;
        lB[j] = (char*)Bs + chunk * 1024;
    }

    int wr64 = (wave >> 1) * 64, wc = wave & 1;
    int lr = lane & 15, q = lane >> 4;
    int l7 = lr & 7;

    f32x4 acc[4][4];
    #pragma unroll
    for (int i = 0; i < 4; i++)
        #pragma unroll
        for (int j = 0; j < 4; j++) acc[i][j] = (f32x4){0.f, 0.f, 0.f, 0.f};

    for (int kb = 0; kb < DIM / BK; kb++){
        int k0 = kb * BK;
        #pragma unroll
        for (int j = 0; j < 4; j++) gload16(a_g[j] + k0, lA[j]);
        #pragma unroll
        for (int j = 0; j < 4; j++) gload16(b_g[j] + k0, lB[j]);
        __syncthreads();
        #pragma unroll
        for (int kk = 0; kk < 2; kk++){
            short8 av[4], bv[4];
            #pragma unroll
            for (int mf = 0; mf < 4; mf++){
                int row = wr64 + mf * 16 + lr;
                int c = kk * 4 + q;
                av[mf] = *(const short8*)((const char*)As + row * 128 + ((c ^ l7) * 16));
            }
            #pragma unroll
            for (int nf = 0; nf < 4; nf++){
                int row = wc * 64 + nf * 16 + lr;
                int c = kk * 4 + q;
                bv[nf] = *(const short8*)((const char*)Bs + row * 128 + ((c ^ l7) * 16));
            }
            #pragma unroll
            for (int mf = 0; mf < 4; mf++)
                #pragma unroll
                for (int nf = 0; nf < 4; nf++)
                    acc[mf][nf] = __builtin_amdgcn_mfma_f32_16x16x32_bf16(av[mf], bv[nf], acc[mf][nf], 0, 0, 0);
        }
        __syncthreads();
    }

    #pragma unroll
    for (int mf = 0; mf < 4; mf++){
        #pragma unroll
        for (int fp = 0; fp < 2; fp++){
            int fcol = f0 + (wc * 2 + fp) * 16 + lr;
            float gb_ = gpb[e * NF + fcol];
            float ub_ = upb[e * NF + fcol];
            #pragma unroll
            for (int r = 0; r < 4; r++){
                int m = wr64 + mf * 16 + q * 4 + r;
                if (row0 + m < nrows){
                    float gv = acc[mf][2 * fp][r] + gb_;
                    float uv = acc[mf][2 * fp + 1][r] + ub_;
                    float z = gv * uv;
                    float h = z / (1.f + __expf(-z));
                    hbuf[((size_t)(lt * TM + m)) * NF + fcol] = f2bf(h);
                }
            }
        }
    }
}

__global__ __launch_bounds__(256) void k_gemm2_dma(
        const unsigned short* __restrict__ hbuf,
        const unsigned short* __restrict__ wd, const float* __restrict__ db,
        const int* __restrict__ pair_token, const float* __restrict__ pair_w,
        const int* __restrict__ ctrl, float* __restrict__ out){
    const int* offsets = ctrl + 8;
    const int* tileOff = ctrl + 17;
    int g = blockIdx.x;
    if (g >= tileOff[NEXP]) return;
    int e = 0;
    while (e < NEXP - 1 && g >= tileOff[e + 1]) e++;
    int row0 = (g - tileOff[e]) * TM;
    int nrows = offsets[e + 1] - offsets[e];
    int base_slot = offsets[e] + row0;
    int n0 = blockIdx.y * TM;
    int lt = blockIdx.x;

    __shared__ __align__(16) unsigned short As[TM][BK];
    __shared__ __align__(16) unsigned short Bs[TM][BK];

    int tid = threadIdx.x;
    int lane = tid & 63;
    int wave = __builtin_amdgcn_readfirstlane(tid >> 6);
    int rsub = lane >> 3;
    int cd = (lane & 7) ^ rsub;

    const unsigned short* a_g[4];
    const unsigned short* b_g[4];
    char* lA[4]; char* lB[4];
    #pragma unroll
    for (int j = 0; j < 4; j++){
        int chunk = wave * 4 + j;
        int row = chunk * 8 + rsub;
        a_g[j] = hbuf + ((size_t)(lt * TM + row)) * NF + cd * 8;
        int d = n0 + row;
        b_g[j] = wd + ((size_t)e * DIM + d) * NF + cd * 8;
        lA[j] = (char*)As + chunk * 1024;
        lB[j] = (char*)Bs + chunk * 1024;
    }

    int wr64 = (wave >> 1) * 64, wc = wave & 1, wc64 = (wave & 1) * 64;
    int lr = lane & 15, q = lane >> 4;
    int l7 = lr & 7;

    f32x4 acc[4][4];
    #pragma unroll
    for (int i = 0; i < 4; i++)
        #pragma unroll
        for (int j = 0; j < 4; j++) acc[i][j] = (f32x4){0.f, 0.f, 0.f, 0.f};

    for (int kb = 0; kb < NF / BK; kb++){
        int k0 = kb * BK;
        #pragma unroll
        for (int j = 0; j < 4; j++) gload16(a_g[j] + k0, lA[j]);
        #pragma unroll
        for (int j = 0; j < 4; j++) gload16(b_g[j] + k0, lB[j]);
        __syncthreads();
        #pragma unroll
        for (int kk = 0; kk < 2; kk++){
            short8 av[4], bv[4];
            #pragma unroll
            for (int mf = 0; mf < 4; mf++){
                int row = wr64 + mf * 16 + lr;
                int c = kk * 4 + q;
                av[mf] = *(const short8*)((const char*)As + row * 128 + ((c ^ l7) * 16));
            }
            #pragma unroll
            for (int nf = 0; nf < 4; nf++){
                int row = wc64 + nf * 16 + lr;
                int c = kk * 4 + q;
                bv[nf] = *(const short8*)((const char*)Bs + row * 128 + ((c ^ l7) * 16));
            }
            #pragma unroll
            for (int mf = 0; mf < 4; mf++)
                #pragma unroll
                for (int nf = 0; nf < 4; nf++)
                    acc[mf][nf] = __builtin_amdgcn_mfma_f32_16x16x32_bf16(av[mf], bv[nf], acc[mf][nf], 0, 0, 0);
        }
        __syncthreads();
    }

    #pragma unroll
    for (int mf = 0; mf < 4; mf++){
        #pragma unroll
        for (int r = 0; r < 4; r++){
            int m = wr64 + mf * 16 + q * 4 + r;
            if (row0 + m < nrows){
                int slot = base_slot + m;
                int tok = pair_token[slot] & (NTOK - 1);
                float w = pair_w[slot];
                #pragma unroll
                for (int nf = 0; nf < 4; nf++){
                    int n = n0 + wc * 64 + nf * 16 + lr;
                    float v = w * (acc[mf][nf][r] + db[e * DIM + n]);
                    atomicAdd(&out[(size_t)tok * DIM + n], v);
                }
            }
        }
    }
}

// ---------------- fallback path (register staging, any ws size) ----------------
template<bool WB, bool XB>
__global__ __launch_bounds__(256) void k_gemm1(
        const float* __restrict__ xf, const unsigned short* __restrict__ xb,
        const unsigned short* __restrict__ wg, const unsigned short* __restrict__ wu,
        const float* __restrict__ wgf, const float* __restrict__ wuf,
        const float* __restrict__ gpb, const float* __restrict__ upb,
        const int* __restrict__ pair_token, const int* __restrict__ ctrl,
        unsigned short* __restrict__ hbuf, int t0){
    const int* offsets = ctrl + 8;
    const int* tileOff = ctrl + 17;
    int g = t0 + blockIdx.x;
    if (g >= tileOff[NEXP]) return;
    int e = 0;
    while (e < NEXP - 1 && g >= tileOff[e + 1]) e++;
    int row0 = (g - tileOff[e]) * TM;
    int nrows = offsets[e + 1] - offsets[e];
    int base_slot = offsets[e] + row0;
    int f0 = blockIdx.y * 64;
    int lt = blockIdx.x;

    __shared__ unsigned short As[TM][ASTRIDE];
    __shared__ unsigned short Bs[TM][ASTRIDE];

    int tid = threadIdx.x;
    int sr = tid >> 3, sc = tid & 7;

    const unsigned short* a_src[4];
    const float* a_srcf[4];
    bool a_val[4];
    #pragma unroll
    for (int it = 0; it < 4; it++){
        int r = it * 32 + sr;
        bool v = (row0 + r) < nrows;
        int tok = v ? (pair_token[base_slot + r] & (NTOK - 1)) : 0;
        a_val[it] = v;
        if (XB) a_src[it]  = xb + (size_t)tok * DIM + sc * 8;
        else    a_srcf[it] = xf + (size_t)tok * DIM + sc * 8;
    }
    const unsigned short* b_src[4];
    const float* b_srcf[4];
    #pragma unroll
    for (int it = 0; it < 4; it++){
        int br = it * 32 + sr;
        int f = f0 + ((br >> 5) << 4) + (br & 15);
        bool up = (br >> 4) & 1;
        size_t woff = ((size_t)e * NF + f) * DIM + sc * 8;
        if (WB) b_src[it]  = (up ? wu : wg) + woff;
        else    b_srcf[it] = (up ? wuf : wgf) + woff;
    }

    int lane = tid & 63, wave = tid >> 6;
    int wr64 = (wave >> 1) * 64, wc = wave & 1, wc64 = wc * 64;
    int lr = lane & 15, q = lane >> 4;

    f32x4 acc[4][4];
    #pragma unroll
    for (int i = 0; i < 4; i++)
        #pragma unroll
        for (int j = 0; j < 4; j++) acc[i][j] = (f32x4){0.f, 0.f, 0.f, 0.f};

    for (int kb = 0; kb < DIM / BK; kb++){
        int k0 = kb * BK;
        #pragma unroll
        for (int it = 0; it < 4; it++){
            uint4 v = make_uint4(0u, 0u, 0u, 0u);
            if (a_val[it]){
                if (XB) v = *(const uint4*)(a_src[it] + k0);
                else    v = cvt8(a_srcf[it] + k0);
            }
            *(uint4*)&As[it * 32 + sr][sc * 8] = v;
        }
        #pragma unroll
        for (int it = 0; it < 4; it++){
            uint4 v;
            if (WB) v = *(const uint4*)(b_src[it] + k0);
            else    v = cvt8(b_srcf[it] + k0);
            *(uint4*)&Bs[it * 32 + sr][sc * 8] = v;
        }
        __syncthreads();
        #pragma unroll
        for (int kk = 0; kk < 2; kk++){
            short8 av[4], bv[4];
            #pragma unroll
            for (int mf = 0; mf < 4; mf++) av[mf] = *(const short8*)&As[wr64 + mf * 16 + lr][kk * 32 + q * 8];
            #pragma unroll
            for (int nf = 0; nf < 4; nf++) bv[nf] = *(const short8*)&Bs[wc64 + nf * 16 + lr][kk * 32 + q * 8];
            #pragma unroll
            for (int mf = 0; mf < 4; mf++)
                #pragma unroll
                for (int nf = 0; nf < 4; nf++)
                    acc[mf][nf] = __builtin_amdgcn_mfma_f32_16x16x32_bf16(av[mf], bv[nf], acc[mf][nf], 0, 0, 0);
        }
        __syncthreads();
    }

    #pragma unroll
    for (int mf = 0; mf < 4; mf++){
        #pragma unroll
        for (int fp = 0; fp < 2; fp++){
            int fcol = f0 + (wc * 2 + fp) * 16 + lr;
            float gb_ = gpb[e * NF + fcol];
            float ub_ = upb[e * NF + fcol];
            #pragma unroll
            for (int r = 0; r < 4; r++){
                int m = wr64 + mf * 16 + q * 4 + r;
                if (row0 + m < nrows){
                    float gv = acc[mf][2 * fp][r] + gb_;
                    float uv = acc[mf][2 * fp + 1][r] + ub_;
                    float z = gv * uv;
                    float h = z / (1.f + __expf(-z));
                    hbuf[((size_t)(lt * TM + m)) * NF + fcol] = f2bf(h);
                }
            }
        }
    }
}

template<bool WB>
__global__ __launch_bounds__(256) void k_gemm2(
        const unsigned short* __restrict__ hbuf,
        const unsigned short* __restrict__ wd, const float* __restrict__ wdf,
        const float* __restrict__ db,
        const int* __restrict__ pair_token, const float* __restrict__ pair_w,
        const int* __restrict__ ctrl, float* __restrict__ out, int t0){
    const int* offsets = ctrl + 8;
    const int* tileOff = ctrl + 17;
    int g = t0 + blockIdx.x;
    if (g >= tileOff[NEXP]) return;
    int e = 0;
    while (e < NEXP - 1 && g >= tileOff[e + 1]) e++;
    int row0 = (g - tileOff[e]) * TM;
    int nrows = offsets[e + 1] - offsets[e];
    int base_slot = offsets[e] + row0;
    int n0 = blockIdx.y * TM;
    int lt = blockIdx.x;

    __shared__ unsigned short As[TM][ASTRIDE];
    __shared__ unsigned short Bs[TM][ASTRIDE];

    int tid = threadIdx.x;
    int sr = tid >> 3, sc = tid & 7;

    const unsigned short* a_src[4]; bool a_val[4];
    #pragma unroll
    for (int it = 0; it < 4; it++){
        int r = it * 32 + sr;
        a_val[it] = (row0 + r) < nrows;
        a_src[it] = hbuf + ((size_t)(lt * TM + r)) * NF + sc * 8;
    }
    const unsigned short* b_src[4];
    const float* b_srcf[4];
    #pragma unroll
    for (int it = 0; it < 4; it++){
        int d = n0 + it * 32 + sr;
        size_t woff = ((size_t)e * DIM + d) * NF + sc * 8;
        if (WB) b_src[it]  = wd + woff;
        else    b_srcf[it] = wdf + woff;
    }

    int lane = tid & 63, wave = tid >> 6;
    int wr64 = (wave >> 1) * 64, wc = wave & 1, wc64 = wc * 64;
    int lr = lane & 15, q = lane >> 4;

    f32x4 acc[4][4];
    #pragma unroll
    for (int i = 0; i < 4; i++)
        #pragma unroll
        for (int j = 0; j < 4; j++) acc[i][j] = (f32x4){0.f, 0.f, 0.f, 0.f};

    for (int kb = 0; kb < NF / BK; kb++){
        int k0 = kb * BK;
        #pragma unroll
        for (int it = 0; it < 4; it++){
            uint4 v = make_uint4(0u, 0u, 0u, 0u);
            if (a_val[it]) v = *(const uint4*)(a_src[it] + k0);
            *(uint4*)&As[it * 32 + sr][sc * 8] = v;
        }
        #pragma unroll
        for (int it = 0; it < 4; it++){
            uint4 v;
            if (WB) v = *(const uint4*)(b_src[it] + k0);
            else    v = cvt8(b_srcf[it] + k0);
            *(uint4*)&Bs[it * 32 + sr][sc * 8] = v;
        }
        __syncthreads();
        #pragma unroll
        for (int kk = 0; kk < 2; kk++){
            short8 av[4], bv[4];
            #pragma unroll
            for (int mf = 0; mf < 4; mf++) av[mf] = *(const short8*)&As[wr64 + mf * 16 + lr][kk * 32 + q * 8];
            #pragma unroll
            for (int nf = 0; nf < 4; nf++) bv[nf] = *(const short8*)&Bs[wc64 + nf * 16 + lr][kk * 32 + q * 8];
            #pragma unroll
            for (int mf = 0; mf < 4; mf++)
                #pragma unroll
                for (int nf = 0; nf < 4; nf++)
                    acc[mf][nf] = __builtin_amdgcn_mfma_f32_16x16x32_bf16(av[mf], bv[nf], acc[mf][nf], 0, 0, 0);
        }
        __syncthreads();
    }

    #pragma unroll
    for (int mf = 0; mf < 4; mf++){
        #pragma unroll
        for (int r = 0; r < 4; r++){
            int m = wr64 + mf * 16 + q * 4 + r;
            if (row0 + m < nrows){
                int slot = base_slot + m;
                int tok = pair_token[slot] & (NTOK - 1);
                float w = pair_w[slot];
                #pragma unroll
                for (int nf = 0; nf < 4; nf++){
                    int n = n0 + wc64 + nf * 16 + lr;
                    float v = w * (acc[mf][nf][r] + db[e * DIM + n]);
                    atomicAdd(&out[(size_t)tok * DIM + n], v);
                }
            }
        }
    }
}

extern "C" void kernel_launch(void* const* d_in, const int* in_sizes, int n_in,
                              void* d_out, int out_size, void* d_ws, size_t ws_size,
                              hipStream_t stream){
    (void)in_sizes; (void)n_in; (void)out_size;
    const float* x      = (const float*)d_in[0];
    const float* gate_w = (const float*)d_in[1];
    const float* gate_b = (const float*)d_in[2];
    const float* up_w   = (const float*)d_in[3];
    const float* up_b   = (const float*)d_in[4];
    const float* gp_w   = (const float*)d_in[5];
    const float* gp_b   = (const float*)d_in[6];
    const float* down_w = (const float*)d_in[7];
    const float* down_b = (const float*)d_in[8];
    float* out = (float*)d_out;
    char* ws = (char*)d_ws;

    const size_t SZ_XB   = (size_t)NTOK * DIM * 2;             // 16.8 MB
    const size_t SZ_W    = (size_t)NEXP * NF * DIM * 2;        // 53.5 MB each
    const size_t TILE_SZ = (size_t)TM * NF * 2;                // 835,584 B

    size_t off = 0;
    int*   ctrl       = (int*)(ws + off);   off += 256;
    int*   pair_token = (int*)(ws + off);   off += (size_t)NPAIR * 4;
    float* pair_w     = (float*)(ws + off); off += (size_t)NPAIR * 4;
    int*   top_idx    = (int*)(ws + off);   off += (size_t)NTOK * 2 * 4;
    float* top_w      = (float*)(ws + off); off += (size_t)NTOK * 2 * 4;

    size_t rem = (ws_size > off) ? (ws_size - off) : 0;
    bool XB = false, WB = false;
    unsigned short* xb = nullptr;
    unsigned short *wg = nullptr, *wu = nullptr, *wd = nullptr;

    if (rem >= SZ_XB + TILE_SZ){
        XB = true;
        xb = (unsigned short*)(ws + off); off += SZ_XB; rem -= SZ_XB;
    }
    if (rem >= 3 * SZ_W + (size_t)MAXTILES * TILE_SZ){
        WB = true;
        wg = (unsigned short*)(ws + off); off += SZ_W;
        wu = (unsigned short*)(ws + off); off += SZ_W;
        wd = (unsigned short*)(ws + off); off += SZ_W;
        rem -= 3 * SZ_W;
    }
    int TC = (int)((rem / TILE_SZ) < (size_t)MAXTILES ? (rem / TILE_SZ) : (size_t)MAXTILES);
    if (TC < 1) TC = 1;
    unsigned short* hbuf = (unsigned short*)(ws + off);
    int NCH = (MAXTILES + TC - 1) / TC;
    bool FAST = XB && WB && (TC == MAXTILES);

    int out_n4 = NTOK * DIM / 4;
    k_zero_f4<<<(out_n4 + 255) / 256, 256, 0, stream>>>((float4*)out, out_n4);
    k_zero_ctrl<<<1, 64, 0, stream>>>(ctrl);
    if (WB){
        int n4 = NEXP * NF * DIM / 4;
        int gc = (n4 + 255) / 256;
        k_cvt<<<gc, 256, 0, stream>>>((const float4*)gp_w,   (uint2*)wg, n4);
        k_cvt<<<gc, 256, 0, stream>>>((const float4*)up_w,   (uint2*)wu, n4);
        k_cvt<<<gc, 256, 0, stream>>>((const float4*)down_w, (uint2*)wd, n4);
    }
    if (XB) k_router<true ><<<NTOK / 4, 256, 0, stream>>>(x, gate_w, gate_b, top_idx, top_w, ctrl, xb);
    else    k_router<false><<<NTOK / 4, 256, 0, stream>>>(x, gate_w, gate_b, top_idx, top_w, ctrl, xb);
    k_prefix<<<1, 1, 0, stream>>>(ctrl);
    k_scatter<<<NTOK / 256, 256, 0, stream>>>(top_idx, top_w, ctrl, pair_token, pair_w);

    if (FAST){
        dim3 g1(MAXTILES, NF / 64);
        dim3 g2(MAXTILES, DIM / TM);
        k_gemm1_dma<<<g1, 256, 0, stream>>>(xb, wg, wu, gp_b, up_b, pair_token, ctrl, hbuf);
        k_gemm2_dma<<<g2, 256, 0, stream>>>(hbuf, wd, down_b, pair_token, pair_w, ctrl, out);
    } else {
        dim3 g1((unsigned)TC, NF / 64);
        dim3 g2((unsigned)TC, DIM / TM);
        for (int c = 0; c < NCH; c++){
            int t0 = c * TC;
            if (WB){
                if (XB) k_gemm1<true, true ><<<g1, 256, 0, stream>>>(x, xb, wg, wu, nullptr, nullptr, gp_b, up_b, pair_token, ctrl, hbuf, t0);
                else    k_gemm1<true, false><<<g1, 256, 0, stream>>>(x, xb, wg, wu, nullptr, nullptr, gp_b, up_b, pair_token, ctrl, hbuf, t0);
                k_gemm2<true ><<<g2, 256, 0, stream>>>(hbuf, wd, nullptr, down_b, pair_token, pair_w, ctrl, out, t0);
            } else {
                if (XB) k_gemm1<false, true ><<<g1, 256, 0, stream>>>(x, xb, nullptr, nullptr, gp_w, up_w, gp_b, up_b, pair_token, ctrl, hbuf, t0);
                else    k_gemm1<false, false><<<g1, 256, 0, stream>>>(x, xb, nullptr, nullptr, gp_w, up_w, gp_b, up_b, pair_token, ctrl, hbuf, t0);
                k_gemm2<false><<<g2, 256, 0, stream>>>(hbuf, nullptr, down_w, down_b, pair_token, pair_w, ctrl, out, t0);
            }
        }
    }
}

// Round 4
// 1017.289 us; speedup vs baseline: 1.3202x; 1.1368x over previous
//
#include <hip/hip_runtime.h>
#include <cstdint>

#define NTOK 8192
#define DIM  1024
#define NEXP 8
#define NF   3264
#define NPAIR (NTOK*2)
#define TM 128
#define BK 64
#define ASTRIDE (BK+8)
#define MAXTILES 136

typedef __attribute__((ext_vector_type(8))) short short8;
typedef __attribute__((ext_vector_type(4))) float f32x4;

__device__ __forceinline__ unsigned short f2bf(float f){
    unsigned u = __float_as_uint(f);
    return (unsigned short)((u + 0x7FFFu + ((u >> 16) & 1u)) >> 16);
}
__device__ __forceinline__ unsigned pk2(float a, float b){
    return (unsigned)f2bf(a) | ((unsigned)f2bf(b) << 16);
}
__device__ __forceinline__ uint4 cvt8(const float* p){
    const float4* q = (const float4*)p;
    float4 a = q[0], b = q[1];
    uint4 r;
    r.x = pk2(a.x, a.y); r.y = pk2(a.z, a.w);
    r.z = pk2(b.x, b.y); r.w = pk2(b.z, b.w);
    return r;
}

// async global->LDS, 16B per lane; LDS dest = wave-uniform base + lane*16
__device__ __forceinline__ void gload16(const void* g, void* l){
    __builtin_amdgcn_global_load_lds(
        (const __attribute__((address_space(1))) unsigned int*)g,
        (__attribute__((address_space(3))) unsigned int*)l,
        16, 0, 0);
}

__global__ __launch_bounds__(256) void k_cvt(const float4* __restrict__ src,
                                             uint2* __restrict__ dst, int n4){
    int i = blockIdx.x * 256 + threadIdx.x;
    if (i >= n4) return;
    float4 a = src[i];
    uint2 r; r.x = pk2(a.x, a.y); r.y = pk2(a.z, a.w);
    dst[i] = r;
}

__global__ __launch_bounds__(256) void k_zero_f4(float4* __restrict__ p, int n4){
    int i = blockIdx.x * 256 + threadIdx.x;
    if (i < n4) p[i] = make_float4(0.f, 0.f, 0.f, 0.f);
}

__global__ void k_zero_ctrl(int* ctrl){
    if (threadIdx.x < 64) ctrl[threadIdx.x] = 0;
}

// ctrl layout: [0..7]=counts, [8..16]=offsets, [17..25]=tileOff, [26..33]=cursor
template<bool XB>
__global__ __launch_bounds__(256) void k_router(const float* __restrict__ x,
        const float* __restrict__ gw, const float* __restrict__ gb,
        int* __restrict__ top_idx, float* __restrict__ top_w, int* __restrict__ ctrl,
        unsigned short* __restrict__ xb){
    int wave = threadIdx.x >> 6;
    int lane = threadIdx.x & 63;
    int n = blockIdx.x * 4 + wave;
    const float* xr = x + (size_t)n * DIM;
    float acc[NEXP];
    #pragma unroll
    for (int e = 0; e < NEXP; e++) acc[e] = 0.f;
    for (int j = lane; j < DIM; j += 64){
        float xv = xr[j];
        if (XB) xb[(size_t)n * DIM + j] = f2bf(xv);
        #pragma unroll
        for (int e = 0; e < NEXP; e++) acc[e] += xv * gw[e * DIM + j];
    }
    #pragma unroll
    for (int e = 0; e < NEXP; e++){
        float v = acc[e];
        #pragma unroll
        for (int off = 32; off > 0; off >>= 1) v += __shfl_xor(v, off);
        acc[e] = v + gb[e];
    }
    if (lane == 0){
        int i0 = 0; float m0 = acc[0];
        #pragma unroll
        for (int e = 1; e < NEXP; e++) if (acc[e] > m0){ m0 = acc[e]; i0 = e; }
        int i1 = -1; float m1 = -3.4e38f;
        #pragma unroll
        for (int e = 0; e < NEXP; e++) if (e != i0 && acc[e] > m1){ m1 = acc[e]; i1 = e; }
        float b  = __expf(m1 - m0);
        float w0 = 1.f / (1.f + b);
        float w1 = b / (1.f + b);
        top_idx[n * 2] = i0; top_idx[n * 2 + 1] = i1;
        top_w[n * 2] = w0;  top_w[n * 2 + 1] = w1;
        atomicAdd(&ctrl[i0], 1);
        atomicAdd(&ctrl[i1], 1);
    }
}

__global__ void k_prefix(int* ctrl){
    int* counts = ctrl; int* offsets = ctrl + 8; int* tileOff = ctrl + 17; int* cursor = ctrl + 26;
    offsets[0] = 0; tileOff[0] = 0;
    for (int e = 0; e < NEXP; e++){
        offsets[e + 1] = offsets[e] + counts[e];
        tileOff[e + 1] = tileOff[e] + (counts[e] + TM - 1) / TM;
        cursor[e] = 0;
    }
}

// LDS-aggregated cursor atomics; also records inverse map slot(token,k).
__global__ __launch_bounds__(256) void k_scatter(const int* __restrict__ top_idx,
        const float* __restrict__ top_w, int* __restrict__ ctrl,
        int* __restrict__ pair_token, float* __restrict__ pair_w,
        int* __restrict__ inv_slot){
    const int* offsets = ctrl + 8;
    int* cursor = ctrl + 26;
    __shared__ int lcnt[NEXP];
    __shared__ int gbase[NEXP];
    int tid = threadIdx.x;
    if (tid < NEXP) lcnt[tid] = 0;
    __syncthreads();
    int n = blockIdx.x * 256 + tid;
    int e0 = top_idx[n * 2];
    int e1 = top_idx[n * 2 + 1];
    int p0 = atomicAdd(&lcnt[e0], 1);
    int p1 = atomicAdd(&lcnt[e1], 1);
    __syncthreads();
    if (tid < NEXP) gbase[tid] = atomicAdd(&cursor[tid], lcnt[tid]);
    __syncthreads();
    int s0 = offsets[e0] + gbase[e0] + p0;
    int s1 = offsets[e1] + gbase[e1] + p1;
    pair_token[s0] = n; pair_w[s0] = top_w[n * 2];
    pair_token[s1] = n; pair_w[s1] = top_w[n * 2 + 1];
    inv_slot[n * 2] = s0; inv_slot[n * 2 + 1] = s1;
}

// out[tok] = ybuf[s0] + ybuf[s1]   (weights & bias already applied in gemm2)
__global__ __launch_bounds__(256) void k_combine(const float* __restrict__ ybuf,
        const int* __restrict__ inv_slot, float* __restrict__ out){
    int t = blockIdx.x;
    int c = threadIdx.x;                 // 0..255, DIM/4 = 256
    int s0 = inv_slot[t * 2], s1 = inv_slot[t * 2 + 1];
    const float4* y0 = (const float4*)(ybuf + (size_t)s0 * DIM);
    const float4* y1 = (const float4*)(ybuf + (size_t)s1 * DIM);
    float4 a = y0[c], b = y1[c];
    float4 r = make_float4(a.x + b.x, a.y + b.y, a.z + b.z, a.w + b.w);
    ((float4*)(out + (size_t)t * DIM))[c] = r;
}

// ---------------- fast path: global_load_lds + swizzled LDS ----------------
// LDS layout: unpadded [128][64] bf16; chunk c (16B) of row r stored at slot c^(r&7).
// Swizzle applied via the global source address, so DMA lane order stays base+lane*16.

__global__ __launch_bounds__(256) void k_gemm1_dma(
        const unsigned short* __restrict__ xb,
        const unsigned short* __restrict__ wg, const unsigned short* __restrict__ wu,
        const float* __restrict__ gpb, const float* __restrict__ upb,
        const int* __restrict__ pair_token, const int* __restrict__ ctrl,
        unsigned short* __restrict__ hbuf){
    const int* offsets = ctrl + 8;
    const int* tileOff = ctrl + 17;
    int g = blockIdx.x;
    if (g >= tileOff[NEXP]) return;
    int e = 0;
    while (e < NEXP - 1 && g >= tileOff[e + 1]) e++;
    int row0 = (g - tileOff[e]) * TM;
    int nrows = offsets[e + 1] - offsets[e];
    int base_slot = offsets[e] + row0;
    int f0 = blockIdx.y * 64;
    int lt = blockIdx.x;

    __shared__ __align__(16) unsigned short As[TM][BK];
    __shared__ __align__(16) unsigned short Bs[TM][BK];

    int tid = threadIdx.x;
    int lane = tid & 63;
    int wave = __builtin_amdgcn_readfirstlane(tid >> 6);
    int rsub = lane >> 3;             // row within 8-row chunk group
    int cd = (lane & 7) ^ rsub;       // swizzled source chunk

    const unsigned short* a_g[4];
    const unsigned short* b_g[4];
    char* lA[4]; char* lB[4];
    #pragma unroll
    for (int j = 0; j < 4; j++){
        int chunk = wave * 4 + j;     // 0..15
        int row = chunk * 8 + rsub;   // 0..127
        int rr = (row0 + row < nrows) ? row : 0;   // clamp: garbage only feeds discarded rows
        int tok = pair_token[base_slot + rr] & (NTOK - 1);
        a_g[j] = xb + (size_t)tok * DIM + cd * 8;
        int f = f0 + ((row >> 5) << 4) + (row & 15);
        int up = (row >> 4) & 1;
        b_g[j] = (up ? wu : wg) + ((size_t)e * NF + f) * DIM + cd * 8;
        lA[j] = (char*)As + chunk * 1024;
        lB[j] = (char*)Bs + chunk * 1024;
    }

    int wr64 = (wave >> 1) * 64, wc = wave & 1;
    int lr = lane & 15, q = lane >> 4;
    int l7 = lr & 7;

    f32x4 acc[4][4];
    #pragma unroll
    for (int i = 0; i < 4; i++)
        #pragma unroll
        for (int j = 0; j < 4; j++) acc[i][j] = (f32x4){0.f, 0.f, 0.f, 0.f};

    for (int kb = 0; kb < DIM / BK; kb++){
        int k0 = kb * BK;
        #pragma unroll
        for (int j = 0; j < 4; j++) gload16(a_g[j] + k0, lA[j]);
        #pragma unroll
        for (int j = 0; j < 4; j++) gload16(b_g[j] + k0, lB[j]);
        __syncthreads();
        #pragma unroll
        for (int kk = 0; kk < 2; kk++){
            short8 av[4], bv[4];
            #pragma unroll
            for (int mf = 0; mf < 4; mf++){
                int row = wr64 + mf * 16 + lr;
                int c = kk * 4 + q;
                av[mf] = *(const short8*)((const char*)As + row * 128 + ((c ^ l7) * 16));
            }
            #pragma unroll
            for (int nf = 0; nf < 4; nf++){
                int row = wc * 64 + nf * 16 + lr;
                int c = kk * 4 + q;
                bv[nf] = *(const short8*)((const char*)Bs + row * 128 + ((c ^ l7) * 16));
            }
            #pragma unroll
            for (int mf = 0; mf < 4; mf++)
                #pragma unroll
                for (int nf = 0; nf < 4; nf++)
                    acc[mf][nf] = __builtin_amdgcn_mfma_f32_16x16x32_bf16(av[mf], bv[nf], acc[mf][nf], 0, 0, 0);
        }
        __syncthreads();
    }

    #pragma unroll
    for (int mf = 0; mf < 4; mf++){
        #pragma unroll
        for (int fp = 0; fp < 2; fp++){
            int fcol = f0 + (wc * 2 + fp) * 16 + lr;
            float gb_ = gpb[e * NF + fcol];
            float ub_ = upb[e * NF + fcol];
            #pragma unroll
            for (int r = 0; r < 4; r++){
                int m = wr64 + mf * 16 + q * 4 + r;
                if (row0 + m < nrows){
                    float gv = acc[mf][2 * fp][r] + gb_;
                    float uv = acc[mf][2 * fp + 1][r] + ub_;
                    float z = gv * uv;
                    float h = z / (1.f + __expf(-z));
                    hbuf[((size_t)(lt * TM + m)) * NF + fcol] = f2bf(h);
                }
            }
        }
    }
}

// GEMM2 fast: ybuf[slot] = w * (h @ downW^T + down_b)  — plain stores, no atomics
__global__ __launch_bounds__(256) void k_gemm2_dma(
        const unsigned short* __restrict__ hbuf,
        const unsigned short* __restrict__ wd, const float* __restrict__ db,
        const float* __restrict__ pair_w,
        const int* __restrict__ ctrl, float* __restrict__ ybuf){
    const int* offsets = ctrl + 8;
    const int* tileOff = ctrl + 17;
    int g = blockIdx.x;
    if (g >= tileOff[NEXP]) return;
    int e = 0;
    while (e < NEXP - 1 && g >= tileOff[e + 1]) e++;
    int row0 = (g - tileOff[e]) * TM;
    int nrows = offsets[e + 1] - offsets[e];
    int base_slot = offsets[e] + row0;
    int n0 = blockIdx.y * TM;
    int lt = blockIdx.x;

    __shared__ __align__(16) unsigned short As[TM][BK];
    __shared__ __align__(16) unsigned short Bs[TM][BK];

    int tid = threadIdx.x;
    int lane = tid & 63;
    int wave = __builtin_amdgcn_readfirstlane(tid >> 6);
    int rsub = lane >> 3;
    int cd = (lane & 7) ^ rsub;

    const unsigned short* a_g[4];
    const unsigned short* b_g[4];
    char* lA[4]; char* lB[4];
    #pragma unroll
    for (int j = 0; j < 4; j++){
        int chunk = wave * 4 + j;
        int row = chunk * 8 + rsub;
        a_g[j] = hbuf + ((size_t)(lt * TM + row)) * NF + cd * 8;
        int d = n0 + row;
        b_g[j] = wd + ((size_t)e * DIM + d) * NF + cd * 8;
        lA[j] = (char*)As + chunk * 1024;
        lB[j] = (char*)Bs + chunk * 1024;
    }

    int wr64 = (wave >> 1) * 64, wc = wave & 1, wc64 = (wave & 1) * 64;
    int lr = lane & 15, q = lane >> 4;
    int l7 = lr & 7;

    f32x4 acc[4][4];
    #pragma unroll
    for (int i = 0; i < 4; i++)
        #pragma unroll
        for (int j = 0; j < 4; j++) acc[i][j] = (f32x4){0.f, 0.f, 0.f, 0.f};

    for (int kb = 0; kb < NF / BK; kb++){
        int k0 = kb * BK;
        #pragma unroll
        for (int j = 0; j < 4; j++) gload16(a_g[j] + k0, lA[j]);
        #pragma unroll
        for (int j = 0; j < 4; j++) gload16(b_g[j] + k0, lB[j]);
        __syncthreads();
        #pragma unroll
        for (int kk = 0; kk < 2; kk++){
            short8 av[4], bv[4];
            #pragma unroll
            for (int mf = 0; mf < 4; mf++){
                int row = wr64 + mf * 16 + lr;
                int c = kk * 4 + q;
                av[mf] = *(const short8*)((const char*)As + row * 128 + ((c ^ l7) * 16));
            }
            #pragma unroll
            for (int nf = 0; nf < 4; nf++){
                int row = wc64 + nf * 16 + lr;
                int c = kk * 4 + q;
                bv[nf] = *(const short8*)((const char*)Bs + row * 128 + ((c ^ l7) * 16));
            }
            #pragma unroll
            for (int mf = 0; mf < 4; mf++)
                #pragma unroll
                for (int nf = 0; nf < 4; nf++)
                    acc[mf][nf] = __builtin_amdgcn_mfma_f32_16x16x32_bf16(av[mf], bv[nf], acc[mf][nf], 0, 0, 0);
        }
        __syncthreads();
    }

    #pragma unroll
    for (int mf = 0; mf < 4; mf++){
        #pragma unroll
        for (int r = 0; r < 4; r++){
            int m = wr64 + mf * 16 + q * 4 + r;
            if (row0 + m < nrows){
                int slot = base_slot + m;
                float w = pair_w[slot];
                float* yr = ybuf + (size_t)slot * DIM;
                #pragma unroll
                for (int nf = 0; nf < 4; nf++){
                    int n = n0 + wc * 64 + nf * 16 + lr;
                    yr[n] = w * (acc[mf][nf][r] + db[e * DIM + n]);
                }
            }
        }
    }
}

// ---------------- fallback path (register staging, any ws size) ----------------
template<bool WB, bool XB>
__global__ __launch_bounds__(256) void k_gemm1(
        const float* __restrict__ xf, const unsigned short* __restrict__ xb,
        const unsigned short* __restrict__ wg, const unsigned short* __restrict__ wu,
        const float* __restrict__ wgf, const float* __restrict__ wuf,
        const float* __restrict__ gpb, const float* __restrict__ upb,
        const int* __restrict__ pair_token, const int* __restrict__ ctrl,
        unsigned short* __restrict__ hbuf, int t0){
    const int* offsets = ctrl + 8;
    const int* tileOff = ctrl + 17;
    int g = t0 + blockIdx.x;
    if (g >= tileOff[NEXP]) return;
    int e = 0;
    while (e < NEXP - 1 && g >= tileOff[e + 1]) e++;
    int row0 = (g - tileOff[e]) * TM;
    int nrows = offsets[e + 1] - offsets[e];
    int base_slot = offsets[e] + row0;
    int f0 = blockIdx.y * 64;
    int lt = blockIdx.x;

    __shared__ unsigned short As[TM][ASTRIDE];
    __shared__ unsigned short Bs[TM][ASTRIDE];

    int tid = threadIdx.x;
    int sr = tid >> 3, sc = tid & 7;

    const unsigned short* a_src[4];
    const float* a_srcf[4];
    bool a_val[4];
    #pragma unroll
    for (int it = 0; it < 4; it++){
        int r = it * 32 + sr;
        bool v = (row0 + r) < nrows;
        int tok = v ? (pair_token[base_slot + r] & (NTOK - 1)) : 0;
        a_val[it] = v;
        if (XB) a_src[it]  = xb + (size_t)tok * DIM + sc * 8;
        else    a_srcf[it] = xf + (size_t)tok * DIM + sc * 8;
    }
    const unsigned short* b_src[4];
    const float* b_srcf[4];
    #pragma unroll
    for (int it = 0; it < 4; it++){
        int br = it * 32 + sr;
        int f = f0 + ((br >> 5) << 4) + (br & 15);
        bool up = (br >> 4) & 1;
        size_t woff = ((size_t)e * NF + f) * DIM + sc * 8;
        if (WB) b_src[it]  = (up ? wu : wg) + woff;
        else    b_srcf[it] = (up ? wuf : wgf) + woff;
    }

    int lane = tid & 63, wave = tid >> 6;
    int wr64 = (wave >> 1) * 64, wc = wave & 1, wc64 = wc * 64;
    int lr = lane & 15, q = lane >> 4;

    f32x4 acc[4][4];
    #pragma unroll
    for (int i = 0; i < 4; i++)
        #pragma unroll
        for (int j = 0; j < 4; j++) acc[i][j] = (f32x4){0.f, 0.f, 0.f, 0.f};

    for (int kb = 0; kb < DIM / BK; kb++){
        int k0 = kb * BK;
        #pragma unroll
        for (int it = 0; it < 4; it++){
            uint4 v = make_uint4(0u, 0u, 0u, 0u);
            if (a_val[it]){
                if (XB) v = *(const uint4*)(a_src[it] + k0);
                else    v = cvt8(a_srcf[it] + k0);
            }
            *(uint4*)&As[it * 32 + sr][sc * 8] = v;
        }
        #pragma unroll
        for (int it = 0; it < 4; it++){
            uint4 v;
            if (WB) v = *(const uint4*)(b_src[it] + k0);
            else    v = cvt8(b_srcf[it] + k0);
            *(uint4*)&Bs[it * 32 + sr][sc * 8] = v;
        }
        __syncthreads();
        #pragma unroll
        for (int kk = 0; kk < 2; kk++){
            short8 av[4], bv[4];
            #pragma unroll
            for (int mf = 0; mf < 4; mf++) av[mf] = *(const short8*)&As[wr64 + mf * 16 + lr][kk * 32 + q * 8];
            #pragma unroll
            for (int nf = 0; nf < 4; nf++) bv[nf] = *(const short8*)&Bs[wc64 + nf * 16 + lr][kk * 32 + q * 8];
            #pragma unroll
            for (int mf = 0; mf < 4; mf++)
                #pragma unroll
                for (int nf = 0; nf < 4; nf++)
                    acc[mf][nf] = __builtin_amdgcn_mfma_f32_16x16x32_bf16(av[mf], bv[nf], acc[mf][nf], 0, 0, 0);
        }
        __syncthreads();
    }

    #pragma unroll
    for (int mf = 0; mf < 4; mf++){
        #pragma unroll
        for (int fp = 0; fp < 2; fp++){
            int fcol = f0 + (wc * 2 + fp) * 16 + lr;
            float gb_ = gpb[e * NF + fcol];
            float ub_ = upb[e * NF + fcol];
            #pragma unroll
            for (int r = 0; r < 4; r++){
                int m = wr64 + mf * 16 + q * 4 + r;
                if (row0 + m < nrows){
                    float gv = acc[mf][2 * fp][r] + gb_;
                    float uv = acc[mf][2 * fp + 1][r] + ub_;
                    float z = gv * uv;
                    float h = z / (1.f + __expf(-z));
                    hbuf[((size_t)(lt * TM + m)) * NF + fcol] = f2bf(h);
                }
            }
        }
    }
}

template<bool WB>
__global__ __launch_bounds__(256) void k_gemm2(
        const unsigned short* __restrict__ hbuf,
        const unsigned short* __restrict__ wd, const float* __restrict__ wdf,
        const float* __restrict__ db,
        const int* __restrict__ pair_token, const float* __restrict__ pair_w,
        const int* __restrict__ ctrl, float* __restrict__ out, int t0){
    const int* offsets = ctrl + 8;
    const int* tileOff = ctrl + 17;
    int g = t0 + blockIdx.x;
    if (g >= tileOff[NEXP]) return;
    int e = 0;
    while (e < NEXP - 1 && g >= tileOff[e + 1]) e++;
    int row0 = (g - tileOff[e]) * TM;
    int nrows = offsets[e + 1] - offsets[e];
    int base_slot = offsets[e] + row0;
    int n0 = blockIdx.y * TM;
    int lt = blockIdx.x;

    __shared__ unsigned short As[TM][ASTRIDE];
    __shared__ unsigned short Bs[TM][ASTRIDE];

    int tid = threadIdx.x;
    int sr = tid >> 3, sc = tid & 7;

    const unsigned short* a_src[4]; bool a_val[4];
    #pragma unroll
    for (int it = 0; it < 4; it++){
        int r = it * 32 + sr;
        a_val[it] = (row0 + r) < nrows;
        a_src[it] = hbuf + ((size_t)(lt * TM + r)) * NF + sc * 8;
    }
    const unsigned short* b_src[4];
    const float* b_srcf[4];
    #pragma unroll
    for (int it = 0; it < 4; it++){
        int d = n0 + it * 32 + sr;
        size_t woff = ((size_t)e * DIM + d) * NF + sc * 8;
        if (WB) b_src[it]  = wd + woff;
        else    b_srcf[it] = wdf + woff;
    }

    int lane = tid & 63, wave = tid >> 6;
    int wr64 = (wave >> 1) * 64, wc = wave & 1, wc64 = wc * 64;
    int lr = lane & 15, q = lane >> 4;

    f32x4 acc[4][4];
    #pragma unroll
    for (int i = 0; i < 4; i++)
        #pragma unroll
        for (int j = 0; j < 4; j++) acc[i][j] = (f32x4){0.f, 0.f, 0.f, 0.f};

    for (int kb = 0; kb < NF / BK; kb++){
        int k0 = kb * BK;
        #pragma unroll
        for (int it = 0; it < 4; it++){
            uint4 v = make_uint4(0u, 0u, 0u, 0u);
            if (a_val[it]) v = *(const uint4*)(a_src[it] + k0);
            *(uint4*)&As[it * 32 + sr][sc * 8] = v;
        }
        #pragma unroll
        for (int it = 0; it < 4; it++){
            uint4 v;
            if (WB) v = *(const uint4*)(b_src[it] + k0);
            else    v = cvt8(b_srcf[it] + k0);
            *(uint4*)&Bs[it * 32 + sr][sc * 8] = v;
        }
        __syncthreads();
        #pragma unroll
        for (int kk = 0; kk < 2; kk++){
            short8 av[4], bv[4];
            #pragma unroll
            for (int mf = 0; mf < 4; mf++) av[mf] = *(const short8*)&As[wr64 + mf * 16 + lr][kk * 32 + q * 8];
            #pragma unroll
            for (int nf = 0; nf < 4; nf++) bv[nf] = *(const short8*)&Bs[wc64 + nf * 16 + lr][kk * 32 + q * 8];
            #pragma unroll
            for (int mf = 0; mf < 4; mf++)
                #pragma unroll
                for (int nf = 0; nf < 4; nf++)
                    acc[mf][nf] = __builtin_amdgcn_mfma_f32_16x16x32_bf16(av[mf], bv[nf], acc[mf][nf], 0, 0, 0);
        }
        __syncthreads();
    }

    #pragma unroll
    for (int mf = 0; mf < 4; mf++){
        #pragma unroll
        for (int r = 0; r < 4; r++){
            int m = wr64 + mf * 16 + q * 4 + r;
            if (row0 + m < nrows){
                int slot = base_slot + m;
                int tok = pair_token[slot] & (NTOK - 1);
                float w = pair_w[slot];
                #pragma unroll
                for (int nf = 0; nf < 4; nf++){
                    int n = n0 + wc64 + nf * 16 + lr;
                    float v = w * (acc[mf][nf][r] + db[e * DIM + n]);
                    atomicAdd(&out[(size_t)tok * DIM + n], v);
                }
            }
        }
    }
}

extern "C" void kernel_launch(void* const* d_in, const int* in_sizes, int n_in,
                              void* d_out, int out_size, void* d_ws, size_t ws_size,
                              hipStream_t stream){
    (void)in_sizes; (void)n_in; (void)out_size;
    const float* x      = (const float*)d_in[0];
    const float* gate_w = (const float*)d_in[1];
    const float* gate_b = (const float*)d_in[2];
    const float* up_w   = (const float*)d_in[3];
    const float* up_b   = (const float*)d_in[4];
    const float* gp_w   = (const float*)d_in[5];
    const float* gp_b   = (const float*)d_in[6];
    const float* down_w = (const float*)d_in[7];
    const float* down_b = (const float*)d_in[8];
    float* out = (float*)d_out;
    char* ws = (char*)d_ws;

    const size_t SZ_XB   = (size_t)NTOK * DIM * 2;             // 16.8 MB
    const size_t SZ_W    = (size_t)NEXP * NF * DIM * 2;        // 53.5 MB each (bf16)
    const size_t TILE_SZ = (size_t)TM * NF * 2;                // 835,584 B

    size_t off = 0;
    int*   ctrl       = (int*)(ws + off);   off += 256;
    int*   pair_token = (int*)(ws + off);   off += (size_t)NPAIR * 4;
    float* pair_w     = (float*)(ws + off); off += (size_t)NPAIR * 4;
    int*   top_idx    = (int*)(ws + off);   off += (size_t)NTOK * 2 * 4;
    float* top_w      = (float*)(ws + off); off += (size_t)NTOK * 2 * 4;
    int*   inv_slot   = (int*)(ws + off);   off += (size_t)NTOK * 2 * 4;

    size_t rem = (ws_size > off) ? (ws_size - off) : 0;
    bool XB = false, WB = false;
    unsigned short* xb = nullptr;
    unsigned short *wg = nullptr, *wu = nullptr, *wd = nullptr;

    if (rem >= SZ_XB + TILE_SZ){
        XB = true;
        xb = (unsigned short*)(ws + off); off += SZ_XB; rem -= SZ_XB;
    }
    if (rem >= 3 * SZ_W + (size_t)MAXTILES * TILE_SZ){
        WB = true;
        wg = (unsigned short*)(ws + off); off += SZ_W;
        wu = (unsigned short*)(ws + off); off += SZ_W;
        wd = (unsigned short*)(ws + off); off += SZ_W;
        rem -= 3 * SZ_W;
    }
    int TC = (int)((rem / TILE_SZ) < (size_t)MAXTILES ? (rem / TILE_SZ) : (size_t)MAXTILES);
    if (TC < 1) TC = 1;
    unsigned short* hbuf = (unsigned short*)(ws + off);
    int NCH = (MAXTILES + TC - 1) / TC;
    bool FAST = XB && WB && (TC == MAXTILES);
    // ybuf (NPAIR*DIM*4 = 67.1 MB) aliases wg+wu (107 MB) — dead after gemm1.
    float* ybuf = (float*)wg;

    int out_n4 = NTOK * DIM / 4;
    k_zero_ctrl<<<1, 64, 0, stream>>>(ctrl);
    if (WB){
        int n4 = NEXP * NF * DIM / 4;
        int gc = (n4 + 255) / 256;
        k_cvt<<<gc, 256, 0, stream>>>((const float4*)gp_w,   (uint2*)wg, n4);
        k_cvt<<<gc, 256, 0, stream>>>((const float4*)up_w,   (uint2*)wu, n4);
        k_cvt<<<gc, 256, 0, stream>>>((const float4*)down_w, (uint2*)wd, n4);
    }
    if (XB) k_router<true ><<<NTOK / 4, 256, 0, stream>>>(x, gate_w, gate_b, top_idx, top_w, ctrl, xb);
    else    k_router<false><<<NTOK / 4, 256, 0, stream>>>(x, gate_w, gate_b, top_idx, top_w, ctrl, xb);
    k_prefix<<<1, 1, 0, stream>>>(ctrl);
    k_scatter<<<NTOK / 256, 256, 0, stream>>>(top_idx, top_w, ctrl, pair_token, pair_w, inv_slot);

    if (FAST){
        dim3 g1(MAXTILES, NF / 64);
        dim3 g2(MAXTILES, DIM / TM);
        k_gemm1_dma<<<g1, 256, 0, stream>>>(xb, wg, wu, gp_b, up_b, pair_token, ctrl, hbuf);
        k_gemm2_dma<<<g2, 256, 0, stream>>>(hbuf, wd, down_b, pair_w, ctrl, ybuf);
        k_combine<<<NTOK, 256, 0, stream>>>(ybuf, inv_slot, out);
    } else {
        k_zero_f4<<<(out_n4 + 255) / 256, 256, 0, stream>>>((float4*)out, out_n4);
        dim3 g1((unsigned)TC, NF / 64);
        dim3 g2((unsigned)TC, DIM / TM);
        for (int c = 0; c < NCH; c++){
            int t0 = c * TC;
            if (WB){
                if (XB) k_gemm1<true, true ><<<g1, 256, 0, stream>>>(x, xb, wg, wu, nullptr, nullptr, gp_b, up_b, pair_token, ctrl, hbuf, t0);
                else    k_gemm1<true, false><<<g1, 256, 0, stream>>>(x, xb, wg, wu, nullptr, nullptr, gp_b, up_b, pair_token, ctrl, hbuf, t0);
                k_gemm2<true ><<<g2, 256, 0, stream>>>(hbuf, wd, nullptr, down_b, pair_token, pair_w, ctrl, out, t0);
            } else {
                if (XB) k_gemm1<false, true ><<<g1, 256, 0, stream>>>(x, xb, nullptr, nullptr, gp_w, up_w, gp_b, up_b, pair_token, ctrl, hbuf, t0);
                else    k_gemm1<false, false><<<g1, 256, 0, stream>>>(x, xb, nullptr, nullptr, gp_w, up_w, gp_b, up_b, pair_token, ctrl, hbuf, t0);
                k_gemm2<false><<<g2, 256, 0, stream>>>(hbuf, nullptr, down_w, down_b, pair_token, pair_w, ctrl, out, t0);
            }
        }
    }
}